// Round 1
// baseline (1368.292 us; speedup 1.0000x reference)
//
#include <hip/hip_runtime.h>
#include <hip/hip_bf16.h>
#include <stdint.h>
#include <stdio.h>

// Problem geometry (fixed by the reference)
#define M_DIM 8192    // 4*2048
#define K_DIM 4096    // IN_FEATURES
#define N_DIM 11008   // OUT_FEATURES

// GEMM tiling (m97 structure: 128x128 tile, BK=64, 4 waves 2x2, 16x16x32 MFMA)
#define BM 128
#define BN 128
#define BK 64
#define TILES_M (M_DIM / BM)   // 64
#define TILES_N (N_DIM / BN)   // 86
#define NWG (TILES_M * TILES_N) // 5504 (divisible by 8 -> simple XCD swizzle is bijective)

typedef __bf16 bf16x8 __attribute__((ext_vector_type(8)));
typedef float f32x4 __attribute__((ext_vector_type(4)));

__device__ __constant__ float kFp4Code[16] = {
    0.0f,           0.0052083333f,  0.6666666666f, 1.0f,
    0.3333333333f,  0.5f,           0.1666666666f, 0.25f,
    -0.0f,          -0.0052083333f, -0.6666666666f, -1.0f,
    -0.3333333333f, -0.5f,          -0.1666666666f, -0.25f
};

// ---------------------------------------------------------------------------
// Kernel 1: FP4 dequant -> bf16 W [N_DIM][K_DIM]
// codes: int32, one code (0..15) per element, flat index = o*K_DIM + k
// absmax: one float per 64-element block (K_DIM % 64 == 0 -> blocks never
// straddle rows). Each thread handles 8 elements: 32B codes in, 16B bf16 out.
// ---------------------------------------------------------------------------
__global__ __launch_bounds__(256) void fp4_dequant_kernel(
    const int* __restrict__ codes, const float* __restrict__ absmax,
    __hip_bfloat16* __restrict__ w)
{
    __shared__ float lut[16];
    if (threadIdx.x < 16) lut[threadIdx.x] = kFp4Code[threadIdx.x];
    __syncthreads();

    const int t = blockIdx.x * 256 + threadIdx.x;  // < 5,636,096
    const int4* cp = (const int4*)codes;
    const int4 c0 = cp[2 * t];
    const int4 c1 = cp[2 * t + 1];
    const float am = absmax[t >> 3];  // (t*8) >> 6

    union { int4 v; __hip_bfloat16 h[8]; } u;
    u.h[0] = __float2bfloat16(lut[c0.x & 15] * am);
    u.h[1] = __float2bfloat16(lut[c0.y & 15] * am);
    u.h[2] = __float2bfloat16(lut[c0.z & 15] * am);
    u.h[3] = __float2bfloat16(lut[c0.w & 15] * am);
    u.h[4] = __float2bfloat16(lut[c1.x & 15] * am);
    u.h[5] = __float2bfloat16(lut[c1.y & 15] * am);
    u.h[6] = __float2bfloat16(lut[c1.z & 15] * am);
    u.h[7] = __float2bfloat16(lut[c1.w & 15] * am);
    ((int4*)w)[t] = u.v;
}

// ---------------------------------------------------------------------------
// Kernel 2: x fp32 -> bf16  [M_DIM][K_DIM]
// ---------------------------------------------------------------------------
__global__ __launch_bounds__(256) void f32_to_bf16_kernel(
    const float* __restrict__ x, __hip_bfloat16* __restrict__ y)
{
    const int t = blockIdx.x * 256 + threadIdx.x;  // < 4,194,304
    const float4* xp = (const float4*)x;
    const float4 a = xp[2 * t];
    const float4 b = xp[2 * t + 1];
    union { int4 v; __hip_bfloat16 h[8]; } u;
    u.h[0] = __float2bfloat16(a.x);
    u.h[1] = __float2bfloat16(a.y);
    u.h[2] = __float2bfloat16(a.z);
    u.h[3] = __float2bfloat16(a.w);
    u.h[4] = __float2bfloat16(b.x);
    u.h[5] = __float2bfloat16(b.y);
    u.h[6] = __float2bfloat16(b.z);
    u.h[7] = __float2bfloat16(b.w);
    ((int4*)y)[t] = u.v;
}

// ---------------------------------------------------------------------------
// Kernel 3: bf16 GEMM, C = A * B^T + bias
// A: [M_DIM][K_DIM] bf16 (x), B: [N_DIM][K_DIM] bf16 (W), C: [M_DIM][N_DIM] f32
// m97 structure: 128x128 tile, BK=64, 4 waves (2x2), each wave computes 64x64
// via 4x4 grid of 16x16x32 MFMA fragments; global_load_lds width-16 staging.
// ---------------------------------------------------------------------------
__global__ __launch_bounds__(256) void gemm_bf16_kernel(
    const __hip_bfloat16* __restrict__ A, const __hip_bfloat16* __restrict__ B,
    const float* __restrict__ bias, float* __restrict__ C)
{
    __shared__ alignas(16) __hip_bfloat16 As[BM * BK];  // 16 KB
    __shared__ alignas(16) __hip_bfloat16 Bs[BN * BK];  // 16 KB

    const int tid = threadIdx.x;
    const int lane = tid & 63;
    const int wid = tid >> 6;

    // XCD-aware bijective swizzle (NWG % 8 == 0). Consecutive same-XCD blocks
    // share tile_n -> B panel (1 MB) stays in that XCD's L2.
    const int wg = blockIdx.x;
    const int swz = (wg & 7) * (NWG / 8) + (wg >> 3);
    const int tile_m = swz % TILES_M;
    const int tile_n = swz / TILES_M;
    const int m0 = tile_m * BM;
    const int n0 = tile_n * BN;

    const int wr = wid >> 1;       // 0..1
    const int wc = wid & 1;        // 0..1
    const int l15 = lane & 15;
    const int kgrp = lane >> 4;    // 0..3

    f32x4 acc[4][4];
#pragma unroll
    for (int i = 0; i < 4; ++i)
#pragma unroll
        for (int j = 0; j < 4; ++j) acc[i][j] = (f32x4){0.f, 0.f, 0.f, 0.f};

    // Staging: tile is 128 rows x 64 cols bf16 = 16 KB = 1024 x 16B chunks.
    // Thread handles 4 chunks: idx = c*256 + tid; row = idx>>3, col8 = idx&7.
    // LDS dest must be wave-uniform base + lane*16 -> base from (c, wid) only.
    for (int kt = 0; kt < K_DIM / BK; ++kt) {
        const int k0 = kt * BK;
#pragma unroll
        for (int c = 0; c < 4; ++c) {
            const int idx = c * 256 + tid;
            const int row = idx >> 3;
            const int col8 = idx & 7;
            const __hip_bfloat16* ga = A + (m0 + row) * K_DIM + k0 + col8 * 8;
            const __hip_bfloat16* gb = B + (n0 + row) * K_DIM + k0 + col8 * 8;
            __hip_bfloat16* la = &As[(c * 256 + wid * 64) * 8];
            __hip_bfloat16* lb = &Bs[(c * 256 + wid * 64) * 8];
            __builtin_amdgcn_global_load_lds(
                (const __attribute__((address_space(1))) void*)ga,
                (__attribute__((address_space(3))) void*)la, 16, 0, 0);
            __builtin_amdgcn_global_load_lds(
                (const __attribute__((address_space(1))) void*)gb,
                (__attribute__((address_space(3))) void*)lb, 16, 0, 0);
        }
        __syncthreads();  // drains vmcnt before barrier (compiler-inserted)

#pragma unroll
        for (int ks = 0; ks < 2; ++ks) {
            bf16x8 a[4], b[4];
#pragma unroll
            for (int m = 0; m < 4; ++m)
                a[m] = *(const bf16x8*)&As[(wr * 64 + m * 16 + l15) * BK + ks * 32 + kgrp * 8];
#pragma unroll
            for (int n = 0; n < 4; ++n)
                b[n] = *(const bf16x8*)&Bs[(wc * 64 + n * 16 + l15) * BK + ks * 32 + kgrp * 8];
#pragma unroll
            for (int m = 0; m < 4; ++m)
#pragma unroll
                for (int n = 0; n < 4; ++n)
                    acc[m][n] = __builtin_amdgcn_mfma_f32_16x16x32_bf16(
                        a[m], b[n], acc[m][n], 0, 0, 0);
        }
        __syncthreads();  // all waves done reading before next stage overwrites
    }

    // Epilogue: C/D layout col = lane&15, row = (lane>>4)*4 + reg (m89-verified)
#pragma unroll
    for (int n = 0; n < 4; ++n) {
        const int col = n0 + wc * 64 + n * 16 + l15;
        const float bv = bias[col];
#pragma unroll
        for (int m = 0; m < 4; ++m) {
            const int rbase = m0 + wr * 64 + m * 16 + kgrp * 4;
#pragma unroll
            for (int r = 0; r < 4; ++r) {
                C[(long long)(rbase + r) * N_DIM + col] = acc[m][n][r] + bv;
            }
        }
    }
}

// ---------------------------------------------------------------------------
extern "C" void kernel_launch(void* const* d_in, const int* in_sizes, int n_in,
                              void* d_out, int out_size, void* d_ws, size_t ws_size,
                              hipStream_t stream)
{
    const float* x      = (const float*)d_in[0];  // [4,2048,4096] f32
    const int*   codes  = (const int*)d_in[1];    // [704512,64] i32
    const float* absmax = (const float*)d_in[2];  // [704512] f32
    const float* bias   = (const float*)d_in[3];  // [11008] f32
    float* out = (float*)d_out;                   // [4,2048,11008] f32

    const size_t w_bytes = (size_t)N_DIM * K_DIM * sizeof(__hip_bfloat16); // 90,177,536
    const size_t x_bytes = (size_t)M_DIM * K_DIM * sizeof(__hip_bfloat16); // 67,108,864
    if (ws_size < w_bytes + x_bytes) {
        fprintf(stderr, "kernel_launch: ws_size=%zu < needed %zu\n",
                ws_size, w_bytes + x_bytes);
        return;
    }
    __hip_bfloat16* wbf = (__hip_bfloat16*)d_ws;
    __hip_bfloat16* xbf = (__hip_bfloat16*)((char*)d_ws + w_bytes);

    // 45,088,768 elems / 8 per thread / 256 per block = 22016 blocks (exact)
    fp4_dequant_kernel<<<dim3(22016), dim3(256), 0, stream>>>(codes, absmax, wbf);
    // 33,554,432 elems / 8 / 256 = 16384 blocks (exact)
    f32_to_bf16_kernel<<<dim3(16384), dim3(256), 0, stream>>>(x, xbf);
    // 64 * 86 = 5504 tiles
    gemm_bf16_kernel<<<dim3(NWG), dim3(256), 0, stream>>>(xbf, wbf, bias, out);
}

// Round 2
// 1279.329 us; speedup vs baseline: 1.0695x; 1.0695x over previous
//
#include <hip/hip_runtime.h>
#include <hip/hip_bf16.h>
#include <stdint.h>
#include <stdio.h>

// Problem geometry (fixed by the reference)
#define M_DIM 8192    // 4*2048
#define K_DIM 4096    // IN_FEATURES
#define N_DIM 11008   // OUT_FEATURES

// GEMM tiling (m97 structure: 128x128 tile, BK=64, 4 waves 2x2, 16x16x32 MFMA)
#define BM 128
#define BN 128
#define BK 64
#define TILES_M (M_DIM / BM)   // 64
#define TILES_N (N_DIM / BN)   // 86
#define NWG (TILES_M * TILES_N) // 5504 (divisible by 8 -> simple XCD swizzle is bijective)

typedef __bf16 bf16x8 __attribute__((ext_vector_type(8)));
typedef float f32x4 __attribute__((ext_vector_type(4)));

__device__ __constant__ float kFp4Code[16] = {
    0.0f,           0.0052083333f,  0.6666666666f, 1.0f,
    0.3333333333f,  0.5f,           0.1666666666f, 0.25f,
    -0.0f,          -0.0052083333f, -0.6666666666f, -1.0f,
    -0.3333333333f, -0.5f,          -0.1666666666f, -0.25f
};

// ---------------------------------------------------------------------------
// Kernel 1: FP4 dequant -> bf16 W [N_DIM][K_DIM]
// ---------------------------------------------------------------------------
__global__ __launch_bounds__(256) void fp4_dequant_kernel(
    const int* __restrict__ codes, const float* __restrict__ absmax,
    __hip_bfloat16* __restrict__ w)
{
    __shared__ float lut[16];
    if (threadIdx.x < 16) lut[threadIdx.x] = kFp4Code[threadIdx.x];
    __syncthreads();

    const int t = blockIdx.x * 256 + threadIdx.x;  // < 5,636,096
    const int4* cp = (const int4*)codes;
    const int4 c0 = cp[2 * t];
    const int4 c1 = cp[2 * t + 1];
    const float am = absmax[t >> 3];  // (t*8) >> 6

    union { int4 v; __hip_bfloat16 h[8]; } u;
    u.h[0] = __float2bfloat16(lut[c0.x & 15] * am);
    u.h[1] = __float2bfloat16(lut[c0.y & 15] * am);
    u.h[2] = __float2bfloat16(lut[c0.z & 15] * am);
    u.h[3] = __float2bfloat16(lut[c0.w & 15] * am);
    u.h[4] = __float2bfloat16(lut[c1.x & 15] * am);
    u.h[5] = __float2bfloat16(lut[c1.y & 15] * am);
    u.h[6] = __float2bfloat16(lut[c1.z & 15] * am);
    u.h[7] = __float2bfloat16(lut[c1.w & 15] * am);
    ((int4*)w)[t] = u.v;
}

// ---------------------------------------------------------------------------
// Kernel 2: x fp32 -> bf16  [M_DIM][K_DIM]
// ---------------------------------------------------------------------------
__global__ __launch_bounds__(256) void f32_to_bf16_kernel(
    const float* __restrict__ x, __hip_bfloat16* __restrict__ y)
{
    const int t = blockIdx.x * 256 + threadIdx.x;  // < 4,194,304
    const float4* xp = (const float4*)x;
    const float4 a = xp[2 * t];
    const float4 b = xp[2 * t + 1];
    union { int4 v; __hip_bfloat16 h[8]; } u;
    u.h[0] = __float2bfloat16(a.x);
    u.h[1] = __float2bfloat16(a.y);
    u.h[2] = __float2bfloat16(a.z);
    u.h[3] = __float2bfloat16(a.w);
    u.h[4] = __float2bfloat16(b.x);
    u.h[5] = __float2bfloat16(b.y);
    u.h[6] = __float2bfloat16(b.z);
    u.h[7] = __float2bfloat16(b.w);
    ((int4*)y)[t] = u.v;
}

// ---------------------------------------------------------------------------
// Kernel 3: bf16 GEMM, C = A * B^T + bias
// A: [M_DIM][K_DIM] bf16 (x), B: [N_DIM][K_DIM] bf16 (W), C: [M_DIM][N_DIM] f32
//
// Bank-conflict fix (rule #21, both-sides-or-neither):
//   Tile rows are 64 bf16 = 128 B = 8 chunks of 16 B. A linear [row][chunk]
//   layout puts the same chunk-column of every row in one 4-bank group ->
//   16-way conflict on ds_read_b128 (round-1: 2.7e8 conflicts).
//   Fix: LDS slot (row, c8) holds global chunk (row, c8 ^ (row&7)).
//   - global_load_lds keeps a LINEAR LDS dest (wave base + lane*16);
//   - the SOURCE address uses the XOR'd chunk column (involution);
//   - fragment reads apply the same XOR.
//   8 consecutive rows then spread one k-column across 8 distinct 4-bank
//   groups -> 16 lanes cover all 32 banks 2-way (free, m136). The source
//   permutation stays inside each 128 B row segment -> coalescing unchanged.
// ---------------------------------------------------------------------------
__global__ __launch_bounds__(256) void gemm_bf16_kernel(
    const __hip_bfloat16* __restrict__ A, const __hip_bfloat16* __restrict__ B,
    const float* __restrict__ bias, float* __restrict__ C)
{
    __shared__ alignas(16) __hip_bfloat16 As[BM * BK];  // 16 KB
    __shared__ alignas(16) __hip_bfloat16 Bs[BN * BK];  // 16 KB

    const int tid = threadIdx.x;
    const int lane = tid & 63;
    const int wid = tid >> 6;

    // XCD-aware bijective swizzle (NWG % 8 == 0). Consecutive same-XCD blocks
    // share tile_n -> B panel (1 MB) stays in that XCD's L2.
    const int wg = blockIdx.x;
    const int swz = (wg & 7) * (NWG / 8) + (wg >> 3);
    const int tile_m = swz % TILES_M;
    const int tile_n = swz / TILES_M;
    const int m0 = tile_m * BM;
    const int n0 = tile_n * BN;

    const int wr = wid >> 1;       // 0..1
    const int wc = wid & 1;        // 0..1
    const int l15 = lane & 15;
    const int kgrp = lane >> 4;    // 0..3

    f32x4 acc[4][4];
#pragma unroll
    for (int i = 0; i < 4; ++i)
#pragma unroll
        for (int j = 0; j < 4; ++j) acc[i][j] = (f32x4){0.f, 0.f, 0.f, 0.f};

    for (int kt = 0; kt < K_DIM / BK; ++kt) {
        const int k0 = kt * BK;
#pragma unroll
        for (int c = 0; c < 4; ++c) {
            const int idx = c * 256 + tid;       // LDS chunk index (linear)
            const int row = idx >> 3;
            const int scol = (idx & 7) ^ (row & 7);   // pre-swizzled source col
            const __hip_bfloat16* ga = A + (m0 + row) * K_DIM + k0 + scol * 8;
            const __hip_bfloat16* gb = B + (n0 + row) * K_DIM + k0 + scol * 8;
            __hip_bfloat16* la = &As[(c * 256 + wid * 64) * 8];
            __hip_bfloat16* lb = &Bs[(c * 256 + wid * 64) * 8];
            __builtin_amdgcn_global_load_lds(
                (const __attribute__((address_space(1))) void*)ga,
                (__attribute__((address_space(3))) void*)la, 16, 0, 0);
            __builtin_amdgcn_global_load_lds(
                (const __attribute__((address_space(1))) void*)gb,
                (__attribute__((address_space(3))) void*)lb, 16, 0, 0);
        }
        __syncthreads();  // drains vmcnt before barrier (compiler-inserted)

#pragma unroll
        for (int ks = 0; ks < 2; ++ks) {
            const int c8 = ks * 4 + kgrp;  // chunk column within the row
            bf16x8 a[4], b[4];
#pragma unroll
            for (int m = 0; m < 4; ++m) {
                const int r = wr * 64 + m * 16 + l15;
                a[m] = *(const bf16x8*)&As[r * BK + ((c8 ^ (r & 7)) * 8)];
            }
#pragma unroll
            for (int n = 0; n < 4; ++n) {
                const int r = wc * 64 + n * 16 + l15;
                b[n] = *(const bf16x8*)&Bs[r * BK + ((c8 ^ (r & 7)) * 8)];
            }
#pragma unroll
            for (int m = 0; m < 4; ++m)
#pragma unroll
                for (int n = 0; n < 4; ++n)
                    acc[m][n] = __builtin_amdgcn_mfma_f32_16x16x32_bf16(
                        a[m], b[n], acc[m][n], 0, 0, 0);
        }
        __syncthreads();  // all waves done reading before next stage overwrites
    }

    // Epilogue: C/D layout col = lane&15, row = (lane>>4)*4 + reg (m89-verified)
#pragma unroll
    for (int n = 0; n < 4; ++n) {
        const int col = n0 + wc * 64 + n * 16 + l15;
        const float bv = bias[col];
#pragma unroll
        for (int m = 0; m < 4; ++m) {
            const int rbase = m0 + wr * 64 + m * 16 + kgrp * 4;
#pragma unroll
            for (int r = 0; r < 4; ++r) {
                C[(long long)(rbase + r) * N_DIM + col] = acc[m][n][r] + bv;
            }
        }
    }
}

// ---------------------------------------------------------------------------
extern "C" void kernel_launch(void* const* d_in, const int* in_sizes, int n_in,
                              void* d_out, int out_size, void* d_ws, size_t ws_size,
                              hipStream_t stream)
{
    const float* x      = (const float*)d_in[0];  // [4,2048,4096] f32
    const int*   codes  = (const int*)d_in[1];    // [704512,64] i32
    const float* absmax = (const float*)d_in[2];  // [704512] f32
    const float* bias   = (const float*)d_in[3];  // [11008] f32
    float* out = (float*)d_out;                   // [4,2048,11008] f32

    const size_t w_bytes = (size_t)N_DIM * K_DIM * sizeof(__hip_bfloat16); // 90,177,536
    const size_t x_bytes = (size_t)M_DIM * K_DIM * sizeof(__hip_bfloat16); // 67,108,864
    if (ws_size < w_bytes + x_bytes) {
        fprintf(stderr, "kernel_launch: ws_size=%zu < needed %zu\n",
                ws_size, w_bytes + x_bytes);
        return;
    }
    __hip_bfloat16* wbf = (__hip_bfloat16*)d_ws;
    __hip_bfloat16* xbf = (__hip_bfloat16*)((char*)d_ws + w_bytes);

    // 45,088,768 elems / 8 per thread / 256 per block = 22016 blocks (exact)
    fp4_dequant_kernel<<<dim3(22016), dim3(256), 0, stream>>>(codes, absmax, wbf);
    // 33,554,432 elems / 8 / 256 = 16384 blocks (exact)
    f32_to_bf16_kernel<<<dim3(16384), dim3(256), 0, stream>>>(x, xbf);
    // 64 * 86 = 5504 tiles
    gemm_bf16_kernel<<<dim3(NWG), dim3(256), 0, stream>>>(xbf, wbf, bias, out);
}

// Round 3
// 895.539 us; speedup vs baseline: 1.5279x; 1.4286x over previous
//
#include <hip/hip_runtime.h>
#include <hip/hip_bf16.h>
#include <stdint.h>
#include <stdio.h>

// Problem geometry (fixed by the reference)
#define M_DIM 8192    // 4*2048
#define K_DIM 4096    // IN_FEATURES
#define N_DIM 11008   // OUT_FEATURES

// 256^2 8-phase template (m201 structure)
#define BM 256
#define BN 256
#define BK 64
#define NT (K_DIM / BK)           // 64 K-tiles
#define TILES_M (M_DIM / BM)      // 32
#define TILES_N (N_DIM / BN)      // 43
#define NWG (TILES_M * TILES_N)   // 1376 (%8==0 -> simple XCD swizzle bijective)

typedef __bf16 bf16x8 __attribute__((ext_vector_type(8)));
typedef float f32x4 __attribute__((ext_vector_type(4)));

__device__ __constant__ float kFp4Code[16] = {
    0.0f,           0.0052083333f,  0.6666666666f, 1.0f,
    0.3333333333f,  0.5f,           0.1666666666f, 0.25f,
    -0.0f,          -0.0052083333f, -0.6666666666f, -1.0f,
    -0.3333333333f, -0.5f,          -0.1666666666f, -0.25f
};

// ---------------------------------------------------------------------------
// Kernel 1: FP4 dequant -> bf16 W [N_DIM][K_DIM]
// ---------------------------------------------------------------------------
__global__ __launch_bounds__(256) void fp4_dequant_kernel(
    const int* __restrict__ codes, const float* __restrict__ absmax,
    __hip_bfloat16* __restrict__ w)
{
    __shared__ float lut[16];
    if (threadIdx.x < 16) lut[threadIdx.x] = kFp4Code[threadIdx.x];
    __syncthreads();

    const int t = blockIdx.x * 256 + threadIdx.x;  // < 5,636,096
    const int4* cp = (const int4*)codes;
    const int4 c0 = cp[2 * t];
    const int4 c1 = cp[2 * t + 1];
    const float am = absmax[t >> 3];

    union { int4 v; __hip_bfloat16 h[8]; } u;
    u.h[0] = __float2bfloat16(lut[c0.x & 15] * am);
    u.h[1] = __float2bfloat16(lut[c0.y & 15] * am);
    u.h[2] = __float2bfloat16(lut[c0.z & 15] * am);
    u.h[3] = __float2bfloat16(lut[c0.w & 15] * am);
    u.h[4] = __float2bfloat16(lut[c1.x & 15] * am);
    u.h[5] = __float2bfloat16(lut[c1.y & 15] * am);
    u.h[6] = __float2bfloat16(lut[c1.z & 15] * am);
    u.h[7] = __float2bfloat16(lut[c1.w & 15] * am);
    ((int4*)w)[t] = u.v;
}

// ---------------------------------------------------------------------------
// Kernel 2: x fp32 -> bf16  [M_DIM][K_DIM]
// ---------------------------------------------------------------------------
__global__ __launch_bounds__(256) void f32_to_bf16_kernel(
    const float* __restrict__ x, __hip_bfloat16* __restrict__ y)
{
    const int t = blockIdx.x * 256 + threadIdx.x;  // < 4,194,304
    const float4* xp = (const float4*)x;
    const float4 a = xp[2 * t];
    const float4 b = xp[2 * t + 1];
    union { int4 v; __hip_bfloat16 h[8]; } u;
    u.h[0] = __float2bfloat16(a.x);
    u.h[1] = __float2bfloat16(a.y);
    u.h[2] = __float2bfloat16(a.z);
    u.h[3] = __float2bfloat16(a.w);
    u.h[4] = __float2bfloat16(b.x);
    u.h[5] = __float2bfloat16(b.y);
    u.h[6] = __float2bfloat16(b.z);
    u.h[7] = __float2bfloat16(b.w);
    ((int4*)y)[t] = u.v;
}

// ---------------------------------------------------------------------------
// Kernel 3: bf16 GEMM, C = A * B^T + bias   (256x256 tile, 8-phase schedule)
//
// LDS (128 KiB): 2 dbuf x { A: 2 halves x [128][64], B: 2 halves x [128][64] }
//   buffer b at b*65536; within buffer: A-lo @0, A-hi @16384, B-lo @32768,
//   B-hi @49152. Each half = 16 KB = 1024 16B-chunks, staged by 512 thr x 2.
// XOR swizzle (round-2-proven, zero conflicts): LDS slot (row,c) holds global
//   chunk (row, c ^ (row&7)); global_load_lds dest stays LINEAR, source is
//   pre-swizzled, reads apply the same XOR (rule #21 both-sides involution).
// Stage stream: element j = 4T+h (h: 0=A-lo,1=B-lo,2=B-hi,3=A-hi of tile T),
//   issued at phase P = j-5 (1/phase). Per-phase vmcnt(6) leaves exactly the
//   3 newest halves in flight => all elements <= P+2 landed; phase P+1 reads
//   need <= P+2. Quadrant order Q0=(Alo,Blo) Q1=(Alo,Bhi) Q2=(Ahi,Bhi)
//   Q3=(Ahi,Blo): every half flies 3 phases before first use; every LDS
//   region has >=1 barrier between last read (tile T-2) and overwrite issue.
//   vmcnt NEVER drains to 0 in the loop (raw s_barrier, not __syncthreads).
// ---------------------------------------------------------------------------
template<int H>
__device__ __forceinline__ void stage_half(
    const __hip_bfloat16* __restrict__ A, const __hip_bfloat16* __restrict__ B,
    char* lds, int T, int m0, int n0, int tid, int wid)
{
    const int Tm = T & (NT - 1);   // wrap (tail phases re-stage tile 0/1; harmless)
    const int buf = T & 1;
    const int regoff = buf * 65536 + (H == 0 ? 0 : H == 3 ? 16384 : H == 1 ? 32768 : 49152);
#pragma unroll
    for (int c = 0; c < 2; ++c) {
        const int idx = c * 512 + tid;          // 0..1023 chunk id (linear LDS)
        const int row = idx >> 3;               // 0..127
        const int scol = (idx & 7) ^ (row & 7); // pre-swizzled source chunk
        const __hip_bfloat16* g;
        if constexpr (H == 0)      g = A + (size_t)(m0 + row) * K_DIM + Tm * 64 + scol * 8;
        else if constexpr (H == 3) g = A + (size_t)(m0 + 128 + row) * K_DIM + Tm * 64 + scol * 8;
        else if constexpr (H == 1) g = B + (size_t)(n0 + row) * K_DIM + Tm * 64 + scol * 8;
        else                       g = B + (size_t)(n0 + 128 + row) * K_DIM + Tm * 64 + scol * 8;
        char* l = lds + regoff + (c * 512 + wid * 64) * 16;  // wave-uniform base + lane*16
        __builtin_amdgcn_global_load_lds(
            (const __attribute__((address_space(1))) void*)g,
            (__attribute__((address_space(3))) void*)l, 16, 0, 0);
    }
}

template<int Q>
__device__ __forceinline__ void do_phase(
    int t, f32x4 (&acc)[4][4][2],
    const __hip_bfloat16* __restrict__ A, const __hip_bfloat16* __restrict__ B,
    char* lds, int m0, int n0, int tid, int wid, int wr, int wc, int l15, int kgrp)
{
    constexpr int mq = Q >> 1;
    constexpr int nq = (Q == 1 || Q == 2) ? 1 : 0;
    const int buf = t & 1;
    const char* Ab = lds + buf * 65536 + mq * 16384;
    const char* Bb = lds + buf * 65536 + 32768 + nq * 16384;

    bf16x8 av[4][2], bv[2][2];
#pragma unroll
    for (int m = 0; m < 4; ++m) {
        const int rA = wr * 64 + m * 16 + l15;
#pragma unroll
        for (int ks = 0; ks < 2; ++ks)
            av[m][ks] = *(const bf16x8*)(Ab + rA * 128 + (((ks * 4 + kgrp) ^ (rA & 7)) * 16));
    }
#pragma unroll
    for (int n = 0; n < 2; ++n) {
        const int rB = wc * 32 + n * 16 + l15;
#pragma unroll
        for (int ks = 0; ks < 2; ++ks)
            bv[n][ks] = *(const bf16x8*)(Bb + rB * 128 + (((ks * 4 + kgrp) ^ (rB & 7)) * 16));
    }

    // stage element j = 4t+Q+5:  Q<3 -> half Q+1 of tile t+1; Q==3 -> half 0 of t+2
    constexpr int H = (Q + 1) & 3;
    stage_half<H>(A, B, lds, t + 1 + (Q == 3 ? 1 : 0), m0, n0, tid, wid);

    asm volatile("s_waitcnt vmcnt(6)" ::: "memory");  // 3 halves stay in flight
    __builtin_amdgcn_s_barrier();
    asm volatile("s_waitcnt lgkmcnt(0)" ::: "memory");
    __builtin_amdgcn_s_setprio(1);
#pragma unroll
    for (int m = 0; m < 4; ++m)
#pragma unroll
        for (int n = 0; n < 2; ++n)
#pragma unroll
            for (int ks = 0; ks < 2; ++ks)
                acc[Q][m][n] = __builtin_amdgcn_mfma_f32_16x16x32_bf16(
                    av[m][ks], bv[n][ks], acc[Q][m][n], 0, 0, 0);
    __builtin_amdgcn_s_setprio(0);
    __builtin_amdgcn_s_barrier();
}

__global__ __launch_bounds__(512, 2) void gemm_bf16_8phase(
    const __hip_bfloat16* __restrict__ A, const __hip_bfloat16* __restrict__ B,
    const float* __restrict__ bias, float* __restrict__ C)
{
    extern __shared__ char lds[];  // 131072 B

    const int tid = threadIdx.x;
    const int lane = tid & 63;
    const int wid = tid >> 6;       // 0..7
    const int wr = wid >> 2;        // 0..1 (M split)
    const int wc = wid & 3;         // 0..3 (N split)
    const int l15 = lane & 15;
    const int kgrp = lane >> 4;

    // XCD-aware bijective swizzle; consecutive same-XCD blocks share tile_n
    // -> 2 MB B panel stays L2-resident.
    const int wg = blockIdx.x;
    const int swz = (wg & 7) * (NWG / 8) + (wg >> 3);
    const int tile_m = swz % TILES_M;
    const int tile_n = swz / TILES_M;
    const int m0 = tile_m * BM;
    const int n0 = tile_n * BN;

    f32x4 acc[4][4][2];
#pragma unroll
    for (int q = 0; q < 4; ++q)
#pragma unroll
        for (int m = 0; m < 4; ++m)
#pragma unroll
            for (int n = 0; n < 2; ++n)
                acc[q][m][n] = (f32x4){0.f, 0.f, 0.f, 0.f};

    // Prologue: issue elements 0..4 (tile0 all halves + tile1 A-lo), then
    // vmcnt(6) -> elements 0,1 (A-lo,B-lo of tile0) landed; barrier propagates.
    stage_half<0>(A, B, lds, 0, m0, n0, tid, wid);
    stage_half<1>(A, B, lds, 0, m0, n0, tid, wid);
    stage_half<2>(A, B, lds, 0, m0, n0, tid, wid);
    stage_half<3>(A, B, lds, 0, m0, n0, tid, wid);
    stage_half<0>(A, B, lds, 1, m0, n0, tid, wid);
    asm volatile("s_waitcnt vmcnt(6)" ::: "memory");
    __builtin_amdgcn_s_barrier();

    for (int t = 0; t < NT; ++t) {
        do_phase<0>(t, acc, A, B, lds, m0, n0, tid, wid, wr, wc, l15, kgrp);
        do_phase<1>(t, acc, A, B, lds, m0, n0, tid, wid, wr, wc, l15, kgrp);
        do_phase<2>(t, acc, A, B, lds, m0, n0, tid, wid, wr, wc, l15, kgrp);
        do_phase<3>(t, acc, A, B, lds, m0, n0, tid, wid, wr, wc, l15, kgrp);
    }

    // Epilogue (C/D layout: col = lane&15, row = (lane>>4)*4 + reg)
#pragma unroll
    for (int q = 0; q < 4; ++q) {
        const int mqe = q >> 1;
        const int nqe = (q == 1 || q == 2) ? 1 : 0;
#pragma unroll
        for (int n = 0; n < 2; ++n) {
            const int col = n0 + nqe * 128 + wc * 32 + n * 16 + l15;
            const float bval = bias[col];
#pragma unroll
            for (int m = 0; m < 4; ++m) {
                const int row = m0 + mqe * 128 + wr * 64 + m * 16 + kgrp * 4;
#pragma unroll
                for (int r = 0; r < 4; ++r)
                    C[(size_t)(row + r) * N_DIM + col] = acc[q][m][n][r] + bval;
            }
        }
    }
}

// ---------------------------------------------------------------------------
extern "C" void kernel_launch(void* const* d_in, const int* in_sizes, int n_in,
                              void* d_out, int out_size, void* d_ws, size_t ws_size,
                              hipStream_t stream)
{
    const float* x      = (const float*)d_in[0];  // [4,2048,4096] f32
    const int*   codes  = (const int*)d_in[1];    // [704512,64] i32
    const float* absmax = (const float*)d_in[2];  // [704512] f32
    const float* bias   = (const float*)d_in[3];  // [11008] f32
    float* out = (float*)d_out;                   // [4,2048,11008] f32

    const size_t w_bytes = (size_t)N_DIM * K_DIM * sizeof(__hip_bfloat16);
    const size_t x_bytes = (size_t)M_DIM * K_DIM * sizeof(__hip_bfloat16);
    if (ws_size < w_bytes + x_bytes) {
        fprintf(stderr, "kernel_launch: ws_size=%zu < needed %zu\n",
                ws_size, w_bytes + x_bytes);
        return;
    }
    __hip_bfloat16* wbf = (__hip_bfloat16*)d_ws;
    __hip_bfloat16* xbf = (__hip_bfloat16*)((char*)d_ws + w_bytes);

    // Allow 128 KiB dynamic LDS (idempotent host-side call; capture-safe).
    hipFuncSetAttribute((const void*)gemm_bf16_8phase,
                        hipFuncAttributeMaxDynamicSharedMemorySize, 131072);

    fp4_dequant_kernel<<<dim3(22016), dim3(256), 0, stream>>>(codes, absmax, wbf);
    f32_to_bf16_kernel<<<dim3(16384), dim3(256), 0, stream>>>(x, xbf);
    gemm_bf16_8phase<<<dim3(NWG), dim3(512), 131072, stream>>>(xbf, wbf, bias, out);
}

// Round 4
// 842.019 us; speedup vs baseline: 1.6250x; 1.0636x over previous
//
#include <hip/hip_runtime.h>
#include <hip/hip_bf16.h>
#include <stdint.h>
#include <stdio.h>

// Problem geometry (fixed by the reference)
#define M_DIM 8192    // 4*2048
#define K_DIM 4096    // IN_FEATURES
#define N_DIM 11008   // OUT_FEATURES

// 256^2 8-phase template (m201 structure)
#define BM 256
#define BN 256
#define BK 64
#define NT (K_DIM / BK)           // 64 K-tiles
#define TILES_M (M_DIM / BM)      // 32
#define TILES_N (N_DIM / BN)      // 43
#define NWG (TILES_M * TILES_N)   // 1376 (%8==0 -> simple XCD swizzle bijective)

typedef __bf16 bf16x8 __attribute__((ext_vector_type(8)));
typedef float f32x4 __attribute__((ext_vector_type(4)));

__device__ __constant__ float kFp4Code[16] = {
    0.0f,           0.0052083333f,  0.6666666666f, 1.0f,
    0.3333333333f,  0.5f,           0.1666666666f, 0.25f,
    -0.0f,          -0.0052083333f, -0.6666666666f, -1.0f,
    -0.3333333333f, -0.5f,          -0.1666666666f, -0.25f
};

// ---------------------------------------------------------------------------
// Kernel 1: FP4 dequant -> bf16 W [N_DIM][K_DIM]
// ---------------------------------------------------------------------------
__global__ __launch_bounds__(256) void fp4_dequant_kernel(
    const int* __restrict__ codes, const float* __restrict__ absmax,
    __hip_bfloat16* __restrict__ w)
{
    __shared__ float lut[16];
    if (threadIdx.x < 16) lut[threadIdx.x] = kFp4Code[threadIdx.x];
    __syncthreads();

    const int t = blockIdx.x * 256 + threadIdx.x;  // < 5,636,096
    const int4* cp = (const int4*)codes;
    const int4 c0 = cp[2 * t];
    const int4 c1 = cp[2 * t + 1];
    const float am = absmax[t >> 3];

    union { int4 v; __hip_bfloat16 h[8]; } u;
    u.h[0] = __float2bfloat16(lut[c0.x & 15] * am);
    u.h[1] = __float2bfloat16(lut[c0.y & 15] * am);
    u.h[2] = __float2bfloat16(lut[c0.z & 15] * am);
    u.h[3] = __float2bfloat16(lut[c0.w & 15] * am);
    u.h[4] = __float2bfloat16(lut[c1.x & 15] * am);
    u.h[5] = __float2bfloat16(lut[c1.y & 15] * am);
    u.h[6] = __float2bfloat16(lut[c1.z & 15] * am);
    u.h[7] = __float2bfloat16(lut[c1.w & 15] * am);
    ((int4*)w)[t] = u.v;
}

// ---------------------------------------------------------------------------
// Kernel 2: x fp32 -> bf16  [M_DIM][K_DIM]
// ---------------------------------------------------------------------------
__global__ __launch_bounds__(256) void f32_to_bf16_kernel(
    const float* __restrict__ x, __hip_bfloat16* __restrict__ y)
{
    const int t = blockIdx.x * 256 + threadIdx.x;  // < 4,194,304
    const float4* xp = (const float4*)x;
    const float4 a = xp[2 * t];
    const float4 b = xp[2 * t + 1];
    union { int4 v; __hip_bfloat16 h[8]; } u;
    u.h[0] = __float2bfloat16(a.x);
    u.h[1] = __float2bfloat16(a.y);
    u.h[2] = __float2bfloat16(a.z);
    u.h[3] = __float2bfloat16(a.w);
    u.h[4] = __float2bfloat16(b.x);
    u.h[5] = __float2bfloat16(b.y);
    u.h[6] = __float2bfloat16(b.z);
    u.h[7] = __float2bfloat16(b.w);
    ((int4*)y)[t] = u.v;
}

// ---------------------------------------------------------------------------
// Kernel 3: bf16 GEMM, C = A * B^T + bias   (256x256 tile, 8-phase schedule)
//
// Round-4 change vs round-3: fragment-holding across phases (m201's actual
// pattern). Quadrant order (0,0)->(0,1)->(1,1)->(1,0) shares A-lo, B-hi,
// A-hi between adjacent phases; only B-lo is re-read at P3.
// LDS reads: 28 ds_read_b128/wave/K-tile (was 48) -- round-3 was LDS-read-BW
// bound (96 reads*1KB/phase ~= 1350cyc/phase at 85 B/cyc/CU = measured phase
// time). Stage/wait/barrier skeleton is UNCHANGED from the verified round-3
// schedule (same issue order, same per-phase vmcnt(6), same invariants).
//
// LDS (128 KiB): 2 dbuf x { A-lo@0, A-hi@16384, B-lo@32768, B-hi@49152 },
// buffer b at b*65536. XOR involution swizzle (round-2-proven, 0 conflicts):
// LDS slot (row,c) holds global chunk (row, c^(row&7)); gload_lds dest LINEAR.
// Stage stream: 1 half per phase; per-phase vmcnt(6) leaves 3 halves in
// flight; every half lands+is confirmed >=1 barrier before first read.
// ---------------------------------------------------------------------------
template<int H>
__device__ __forceinline__ void stage_half(
    const __hip_bfloat16* __restrict__ A, const __hip_bfloat16* __restrict__ B,
    char* lds, int T, int m0, int n0, int tid, int wid)
{
    const int Tm = T & (NT - 1);   // wrap (tail phases re-stage tile 0/1; harmless)
    const int buf = T & 1;
    const int regoff = buf * 65536 + (H == 0 ? 0 : H == 3 ? 16384 : H == 1 ? 32768 : 49152);
#pragma unroll
    for (int c = 0; c < 2; ++c) {
        const int idx = c * 512 + tid;          // 0..1023 chunk id (linear LDS)
        const int row = idx >> 3;               // 0..127
        const int scol = (idx & 7) ^ (row & 7); // pre-swizzled source chunk
        const __hip_bfloat16* g;
        if constexpr (H == 0)      g = A + (size_t)(m0 + row) * K_DIM + Tm * 64 + scol * 8;
        else if constexpr (H == 3) g = A + (size_t)(m0 + 128 + row) * K_DIM + Tm * 64 + scol * 8;
        else if constexpr (H == 1) g = B + (size_t)(n0 + row) * K_DIM + Tm * 64 + scol * 8;
        else                       g = B + (size_t)(n0 + 128 + row) * K_DIM + Tm * 64 + scol * 8;
        char* l = lds + regoff + (c * 512 + wid * 64) * 16;  // wave-uniform base + lane*16
        __builtin_amdgcn_global_load_lds(
            (const __attribute__((address_space(1))) void*)g,
            (__attribute__((address_space(3))) void*)l, 16, 0, 0);
    }
}

__device__ __forceinline__ void load_frags_A(
    const char* base, int wr, int l15, int kgrp, bf16x8 (&v)[4][2])
{
#pragma unroll
    for (int m = 0; m < 4; ++m) {
        const int r = wr * 64 + m * 16 + l15;
#pragma unroll
        for (int ks = 0; ks < 2; ++ks)
            v[m][ks] = *(const bf16x8*)(base + r * 128 + (((ks * 4 + kgrp) ^ (r & 7)) * 16));
    }
}

__device__ __forceinline__ void load_frags_B(
    const char* base, int wc, int l15, int kgrp, bf16x8 (&v)[2][2])
{
#pragma unroll
    for (int n = 0; n < 2; ++n) {
        const int r = wc * 32 + n * 16 + l15;
#pragma unroll
        for (int ks = 0; ks < 2; ++ks)
            v[n][ks] = *(const bf16x8*)(base + r * 128 + (((ks * 4 + kgrp) ^ (r & 7)) * 16));
    }
}

__device__ __forceinline__ void mfma_quad(
    f32x4 (&accq)[4][2], bf16x8 (&av)[4][2], bf16x8 (&bv)[2][2])
{
    __builtin_amdgcn_s_setprio(1);
#pragma unroll
    for (int m = 0; m < 4; ++m)
#pragma unroll
        for (int n = 0; n < 2; ++n)
#pragma unroll
            for (int ks = 0; ks < 2; ++ks)
                accq[m][n] = __builtin_amdgcn_mfma_f32_16x16x32_bf16(
                    av[m][ks], bv[n][ks], accq[m][n], 0, 0, 0);
    __builtin_amdgcn_s_setprio(0);
}

#define PHASE_SYNC()                                        \
    asm volatile("s_waitcnt vmcnt(6)" ::: "memory");        \
    __builtin_amdgcn_s_barrier();                           \
    asm volatile("s_waitcnt lgkmcnt(0)" ::: "memory")

__global__ __launch_bounds__(512, 2) void gemm_bf16_8phase(
    const __hip_bfloat16* __restrict__ A, const __hip_bfloat16* __restrict__ B,
    const float* __restrict__ bias, float* __restrict__ C)
{
    extern __shared__ char lds[];  // 131072 B

    const int tid = threadIdx.x;
    const int lane = tid & 63;
    const int wid = tid >> 6;       // 0..7
    const int wr = wid >> 2;        // 0..1 (M split)
    const int wc = wid & 3;         // 0..3 (N split)
    const int l15 = lane & 15;
    const int kgrp = lane >> 4;

    // XCD-aware bijective swizzle; consecutive same-XCD blocks share tile_n
    // -> 2 MB B panel stays L2-resident.
    const int wg = blockIdx.x;
    const int swz = (wg & 7) * (NWG / 8) + (wg >> 3);
    const int tile_m = swz % TILES_M;
    const int tile_n = swz / TILES_M;
    const int m0 = tile_m * BM;
    const int n0 = tile_n * BN;

    // acc quadrants: 0=(0,0) 1=(0,1) 2=(1,1) 3=(1,0)  (mq,nq)
    f32x4 acc[4][4][2];
#pragma unroll
    for (int q = 0; q < 4; ++q)
#pragma unroll
        for (int m = 0; m < 4; ++m)
#pragma unroll
            for (int n = 0; n < 2; ++n)
                acc[q][m][n] = (f32x4){0.f, 0.f, 0.f, 0.f};

    // Prologue: elements 0..4 (tile0 all halves + tile1 A-lo); vmcnt(6)
    // confirms A-lo(0), B-lo(0) landed; barrier propagates to all waves.
    stage_half<0>(A, B, lds, 0, m0, n0, tid, wid);
    stage_half<1>(A, B, lds, 0, m0, n0, tid, wid);
    stage_half<2>(A, B, lds, 0, m0, n0, tid, wid);
    stage_half<3>(A, B, lds, 0, m0, n0, tid, wid);
    stage_half<0>(A, B, lds, 1, m0, n0, tid, wid);
    asm volatile("s_waitcnt vmcnt(6)" ::: "memory");
    __builtin_amdgcn_s_barrier();

    for (int t = 0; t < NT; ++t) {
        const int buf = t & 1;
        const char* Abase = lds + buf * 65536;
        const char* Bbase = lds + buf * 65536 + 32768;

        bf16x8 avLo[4][2], avHi[4][2], bvLo[2][2], bvHi[2][2], bvLo2[2][2];

        // ---- P0: quadrant (0,0): read A-lo + B-lo (12 ds_read_b128) ----
        load_frags_A(Abase,         wr, l15, kgrp, avLo);
        load_frags_B(Bbase,         wc, l15, kgrp, bvLo);
        stage_half<1>(A, B, lds, t + 1, m0, n0, tid, wid);   // B-lo(t+1)
        PHASE_SYNC();
        mfma_quad(acc[0], avLo, bvLo);
        __builtin_amdgcn_s_barrier();

        // ---- P1: quadrant (0,1): read B-hi only (4); A-lo held ----
        load_frags_B(Bbase + 16384, wc, l15, kgrp, bvHi);
        stage_half<2>(A, B, lds, t + 1, m0, n0, tid, wid);   // B-hi(t+1)
        PHASE_SYNC();
        mfma_quad(acc[1], avLo, bvHi);
        __builtin_amdgcn_s_barrier();

        // ---- P2: quadrant (1,1): read A-hi only (8); B-hi held ----
        load_frags_A(Abase + 16384, wr, l15, kgrp, avHi);
        stage_half<3>(A, B, lds, t + 1, m0, n0, tid, wid);   // A-hi(t+1)
        PHASE_SYNC();
        mfma_quad(acc[2], avHi, bvHi);
        __builtin_amdgcn_s_barrier();

        // ---- P3: quadrant (1,0): re-read B-lo (4); A-hi held ----
        load_frags_B(Bbase,         wc, l15, kgrp, bvLo2);
        stage_half<0>(A, B, lds, t + 2, m0, n0, tid, wid);   // A-lo(t+2)
        PHASE_SYNC();
        mfma_quad(acc[3], avHi, bvLo2);
        __builtin_amdgcn_s_barrier();
    }

    // Epilogue (C/D layout: col = lane&15, row = (lane>>4)*4 + reg).
    // Nontemporal stores: C is written once, never re-read by this kernel --
    // keep the 360 MB stream from evicting A/B panels out of L3.
#pragma unroll
    for (int q = 0; q < 4; ++q) {
        const int mqe = q >> 1;
        const int nqe = (q == 1 || q == 2) ? 1 : 0;
#pragma unroll
        for (int n = 0; n < 2; ++n) {
            const int col = n0 + nqe * 128 + wc * 32 + n * 16 + l15;
            const float bval = bias[col];
#pragma unroll
            for (int m = 0; m < 4; ++m) {
                const int row = m0 + mqe * 128 + wr * 64 + m * 16 + kgrp * 4;
#pragma unroll
                for (int r = 0; r < 4; ++r)
                    __builtin_nontemporal_store(acc[q][m][n][r] + bval,
                        &C[(size_t)(row + r) * N_DIM + col]);
            }
        }
    }
}

// ---------------------------------------------------------------------------
extern "C" void kernel_launch(void* const* d_in, const int* in_sizes, int n_in,
                              void* d_out, int out_size, void* d_ws, size_t ws_size,
                              hipStream_t stream)
{
    const float* x      = (const float*)d_in[0];  // [4,2048,4096] f32
    const int*   codes  = (const int*)d_in[1];    // [704512,64] i32
    const float* absmax = (const float*)d_in[2];  // [704512] f32
    const float* bias   = (const float*)d_in[3];  // [11008] f32
    float* out = (float*)d_out;                   // [4,2048,11008] f32

    const size_t w_bytes = (size_t)N_DIM * K_DIM * sizeof(__hip_bfloat16);
    const size_t x_bytes = (size_t)M_DIM * K_DIM * sizeof(__hip_bfloat16);
    if (ws_size < w_bytes + x_bytes) {
        fprintf(stderr, "kernel_launch: ws_size=%zu < needed %zu\n",
                ws_size, w_bytes + x_bytes);
        return;
    }
    __hip_bfloat16* wbf = (__hip_bfloat16*)d_ws;
    __hip_bfloat16* xbf = (__hip_bfloat16*)((char*)d_ws + w_bytes);

    // Allow 128 KiB dynamic LDS (idempotent host-side call; capture-safe).
    hipFuncSetAttribute((const void*)gemm_bf16_8phase,
                        hipFuncAttributeMaxDynamicSharedMemorySize, 131072);

    fp4_dequant_kernel<<<dim3(22016), dim3(256), 0, stream>>>(codes, absmax, wbf);
    f32_to_bf16_kernel<<<dim3(16384), dim3(256), 0, stream>>>(x, xbf);
    gemm_bf16_8phase<<<dim3(NWG), dim3(512), 131072, stream>>>(xbf, wbf, bias, out);
}

// Round 5
// 834.086 us; speedup vs baseline: 1.6405x; 1.0095x over previous
//
#include <hip/hip_runtime.h>
#include <hip/hip_bf16.h>
#include <stdint.h>
#include <stdio.h>

// Problem geometry (fixed by the reference)
#define M_DIM 8192    // 4*2048
#define K_DIM 4096    // IN_FEATURES
#define N_DIM 11008   // OUT_FEATURES

// 256^2 8-phase template (m201 structure)
#define BM 256
#define BN 256
#define BK 64
#define NT (K_DIM / BK)           // 64 K-tiles (power of 2 -> & wrap ok)
#define TILES_M (M_DIM / BM)      // 32
#define TILES_N (N_DIM / BN)      // 43
#define NWG (TILES_M * TILES_N)   // 1376 (%8==0 -> simple XCD swizzle bijective)

typedef __bf16 bf16x8 __attribute__((ext_vector_type(8)));
typedef float f32x4 __attribute__((ext_vector_type(4)));

__device__ __constant__ float kFp4Code[16] = {
    0.0f,           0.0052083333f,  0.6666666666f, 1.0f,
    0.3333333333f,  0.5f,           0.1666666666f, 0.25f,
    -0.0f,          -0.0052083333f, -0.6666666666f, -1.0f,
    -0.3333333333f, -0.5f,          -0.1666666666f, -0.25f
};

// ---------------------------------------------------------------------------
// Kernel 1: FP4 dequant -> bf16 W [N_DIM][K_DIM]
// ---------------------------------------------------------------------------
__global__ __launch_bounds__(256) void fp4_dequant_kernel(
    const int* __restrict__ codes, const float* __restrict__ absmax,
    __hip_bfloat16* __restrict__ w)
{
    __shared__ float lut[16];
    if (threadIdx.x < 16) lut[threadIdx.x] = kFp4Code[threadIdx.x];
    __syncthreads();

    const int t = blockIdx.x * 256 + threadIdx.x;  // < 5,636,096
    const int4* cp = (const int4*)codes;
    const int4 c0 = cp[2 * t];
    const int4 c1 = cp[2 * t + 1];
    const float am = absmax[t >> 3];

    union { int4 v; __hip_bfloat16 h[8]; } u;
    u.h[0] = __float2bfloat16(lut[c0.x & 15] * am);
    u.h[1] = __float2bfloat16(lut[c0.y & 15] * am);
    u.h[2] = __float2bfloat16(lut[c0.z & 15] * am);
    u.h[3] = __float2bfloat16(lut[c0.w & 15] * am);
    u.h[4] = __float2bfloat16(lut[c1.x & 15] * am);
    u.h[5] = __float2bfloat16(lut[c1.y & 15] * am);
    u.h[6] = __float2bfloat16(lut[c1.z & 15] * am);
    u.h[7] = __float2bfloat16(lut[c1.w & 15] * am);
    ((int4*)w)[t] = u.v;
}

// ---------------------------------------------------------------------------
// Kernel 2: x fp32 -> bf16  [M_DIM][K_DIM]
// ---------------------------------------------------------------------------
__global__ __launch_bounds__(256) void f32_to_bf16_kernel(
    const float* __restrict__ x, __hip_bfloat16* __restrict__ y)
{
    const int t = blockIdx.x * 256 + threadIdx.x;  // < 4,194,304
    const float4* xp = (const float4*)x;
    const float4 a = xp[2 * t];
    const float4 b = xp[2 * t + 1];
    union { int4 v; __hip_bfloat16 h[8]; } u;
    u.h[0] = __float2bfloat16(a.x);
    u.h[1] = __float2bfloat16(a.y);
    u.h[2] = __float2bfloat16(a.z);
    u.h[3] = __float2bfloat16(a.w);
    u.h[4] = __float2bfloat16(b.x);
    u.h[5] = __float2bfloat16(b.y);
    u.h[6] = __float2bfloat16(b.z);
    u.h[7] = __float2bfloat16(b.w);
    ((int4*)y)[t] = u.v;
}

// ---------------------------------------------------------------------------
// Kernel 3: bf16 GEMM, C = A * B^T + bias   (256x256 tile, 8-phase schedule)
//
// Round-5 change vs round-4 (T4, counted-vmcnt once per tile — the m218 lever):
//   vmcnt(6) ONLY at P3 of each K-tile (was: every phase). Stage issue re-timed
//   one slot earlier so the 4-phase confirm horizon covers all reads:
//     tile s's halves issue at P1(s-2): A-lo, P2(s-2): B-lo, P3(s-2): B-hi,
//     P0(s-1): A-hi.   In-loop: P0(t) stages A-hi(t+1); P1: A-lo(t+2);
//     P2: B-lo(t+2); P3: B-hi(t+2).
//   Invariants (checked per half):
//   - P3(t)'s vmcnt(6) leaves exactly {A-lo(t+2),B-lo(t+2),B-hi(t+2)} in
//     flight -> everything read during tile t+1 (incl. A-hi(t+1)@P0(t)) is
//     confirmed landed.
//   - Region overwrite: last ds_read of A-lo/B-lo = P0, B-hi = P1, A-hi = P2;
//     overwrite issues at P1/P2/P3/P0(next) resp. -> >=1 barrier between.
//     (B-lo now HELD in registers across the tile: no P3 re-read -> region
//     free after P0, and 4 fewer ds_read_b128 per wave per tile: 28 -> 24.)
//   - vmcnt never drains to 0 in the loop; raw s_barrier, not __syncthreads.
//
// LDS (128 KiB): 2 dbuf x { A-lo@0, A-hi@16384, B-lo@32768, B-hi@49152 },
// buffer b at b*65536. XOR involution swizzle (round-2-proven, 0 conflicts):
// LDS slot (row,c) holds global chunk (row, c^(row&7)); gload_lds dest LINEAR.
// ---------------------------------------------------------------------------
template<int H>
__device__ __forceinline__ void stage_half(
    const __hip_bfloat16* __restrict__ A, const __hip_bfloat16* __restrict__ B,
    char* lds, int T, int m0, int n0, int tid, int wid)
{
    const int Tm = T & (NT - 1);   // wrap (tail phases re-stage tile 0/1; harmless)
    const int buf = T & 1;
    const int regoff = buf * 65536 + (H == 0 ? 0 : H == 3 ? 16384 : H == 1 ? 32768 : 49152);
#pragma unroll
    for (int c = 0; c < 2; ++c) {
        const int idx = c * 512 + tid;          // 0..1023 chunk id (linear LDS)
        const int row = idx >> 3;               // 0..127
        const int scol = (idx & 7) ^ (row & 7); // pre-swizzled source chunk
        const __hip_bfloat16* g;
        if constexpr (H == 0)      g = A + (size_t)(m0 + row) * K_DIM + Tm * 64 + scol * 8;
        else if constexpr (H == 3) g = A + (size_t)(m0 + 128 + row) * K_DIM + Tm * 64 + scol * 8;
        else if constexpr (H == 1) g = B + (size_t)(n0 + row) * K_DIM + Tm * 64 + scol * 8;
        else                       g = B + (size_t)(n0 + 128 + row) * K_DIM + Tm * 64 + scol * 8;
        char* l = lds + regoff + (c * 512 + wid * 64) * 16;  // wave-uniform base + lane*16
        __builtin_amdgcn_global_load_lds(
            (const __attribute__((address_space(1))) void*)g,
            (__attribute__((address_space(3))) void*)l, 16, 0, 0);
    }
}

__device__ __forceinline__ void load_frags_A(
    const char* base, int wr, int l15, int kgrp, bf16x8 (&v)[4][2])
{
#pragma unroll
    for (int m = 0; m < 4; ++m) {
        const int r = wr * 64 + m * 16 + l15;
#pragma unroll
        for (int ks = 0; ks < 2; ++ks)
            v[m][ks] = *(const bf16x8*)(base + r * 128 + (((ks * 4 + kgrp) ^ (r & 7)) * 16));
    }
}

__device__ __forceinline__ void load_frags_B(
    const char* base, int wc, int l15, int kgrp, bf16x8 (&v)[2][2])
{
#pragma unroll
    for (int n = 0; n < 2; ++n) {
        const int r = wc * 32 + n * 16 + l15;
#pragma unroll
        for (int ks = 0; ks < 2; ++ks)
            v[n][ks] = *(const bf16x8*)(base + r * 128 + (((ks * 4 + kgrp) ^ (r & 7)) * 16));
    }
}

__device__ __forceinline__ void mfma_quad(
    f32x4 (&accq)[4][2], bf16x8 (&av)[4][2], bf16x8 (&bv)[2][2])
{
    __builtin_amdgcn_s_setprio(1);
#pragma unroll
    for (int m = 0; m < 4; ++m)
#pragma unroll
        for (int n = 0; n < 2; ++n)
#pragma unroll
            for (int ks = 0; ks < 2; ++ks)
                accq[m][n] = __builtin_amdgcn_mfma_f32_16x16x32_bf16(
                    av[m][ks], bv[n][ks], accq[m][n], 0, 0, 0);
    __builtin_amdgcn_s_setprio(0);
}

__global__ __launch_bounds__(512, 2) void gemm_bf16_8phase(
    const __hip_bfloat16* __restrict__ A, const __hip_bfloat16* __restrict__ B,
    const float* __restrict__ bias, float* __restrict__ C)
{
    extern __shared__ char lds[];  // 131072 B

    const int tid = threadIdx.x;
    const int lane = tid & 63;
    const int wid = tid >> 6;       // 0..7
    const int wr = wid >> 2;        // 0..1 (M split)
    const int wc = wid & 3;         // 0..3 (N split)
    const int l15 = lane & 15;
    const int kgrp = lane >> 4;

    // XCD-aware bijective swizzle; consecutive same-XCD blocks share tile_n
    // -> 2 MB B panel stays L2-resident.
    const int wg = blockIdx.x;
    const int swz = (wg & 7) * (NWG / 8) + (wg >> 3);
    const int tile_m = swz % TILES_M;
    const int tile_n = swz / TILES_M;
    const int m0 = tile_m * BM;
    const int n0 = tile_n * BN;

    // acc quadrants: 0=(0,0) 1=(0,1) 2=(1,1) 3=(1,0)  (mq,nq)
    f32x4 acc[4][4][2];
#pragma unroll
    for (int q = 0; q < 4; ++q)
#pragma unroll
        for (int m = 0; m < 4; ++m)
#pragma unroll
            for (int n = 0; n < 2; ++n)
                acc[q][m][n] = (f32x4){0.f, 0.f, 0.f, 0.f};

    // Prologue: 7 halves in steady-state slot order
    //   (slots P1(-2)..P3(-2), P0(-1)..P3(-1)); A-hi(1) comes in-loop at P0(0).
    stage_half<0>(A, B, lds, 0, m0, n0, tid, wid);  // A-lo(0)
    stage_half<1>(A, B, lds, 0, m0, n0, tid, wid);  // B-lo(0)
    stage_half<2>(A, B, lds, 0, m0, n0, tid, wid);  // B-hi(0)
    stage_half<3>(A, B, lds, 0, m0, n0, tid, wid);  // A-hi(0)
    stage_half<0>(A, B, lds, 1, m0, n0, tid, wid);  // A-lo(1)
    stage_half<1>(A, B, lds, 1, m0, n0, tid, wid);  // B-lo(1)
    stage_half<2>(A, B, lds, 1, m0, n0, tid, wid);  // B-hi(1)
    asm volatile("s_waitcnt vmcnt(6)" ::: "memory"); // tile-0's 4 halves landed
    __builtin_amdgcn_s_barrier();

    for (int t = 0; t < NT; ++t) {
        const int buf = t & 1;
        const char* Abase = lds + buf * 65536;
        const char* Bbase = lds + buf * 65536 + 32768;

        bf16x8 avLo[4][2], avHi[4][2], bvLo[2][2], bvHi[2][2];

        // ---- P0: Q(0,0): read A-lo + B-lo (12); stage A-hi(t+1) ----
        load_frags_A(Abase, wr, l15, kgrp, avLo);
        load_frags_B(Bbase, wc, l15, kgrp, bvLo);
        stage_half<3>(A, B, lds, t + 1, m0, n0, tid, wid);
        __builtin_amdgcn_s_barrier();
        asm volatile("s_waitcnt lgkmcnt(0)" ::: "memory");
        mfma_quad(acc[0], avLo, bvLo);
        __builtin_amdgcn_s_barrier();

        // ---- P1: Q(0,1): read B-hi (4); stage A-lo(t+2); A-lo held ----
        load_frags_B(Bbase + 16384, wc, l15, kgrp, bvHi);
        stage_half<0>(A, B, lds, t + 2, m0, n0, tid, wid);
        __builtin_amdgcn_s_barrier();
        asm volatile("s_waitcnt lgkmcnt(0)" ::: "memory");
        mfma_quad(acc[1], avLo, bvHi);
        __builtin_amdgcn_s_barrier();

        // ---- P2: Q(1,1): read A-hi (8); stage B-lo(t+2); B-hi held ----
        load_frags_A(Abase + 16384, wr, l15, kgrp, avHi);
        stage_half<1>(A, B, lds, t + 2, m0, n0, tid, wid);
        __builtin_amdgcn_s_barrier();
        asm volatile("s_waitcnt lgkmcnt(0)" ::: "memory");
        mfma_quad(acc[2], avHi, bvHi);
        __builtin_amdgcn_s_barrier();

        // ---- P3: Q(1,0): NO ds_read (A-hi, B-lo held); stage B-hi(t+2);
        //      the ONE vmcnt per tile: 3 newest halves stay in flight ----
        stage_half<2>(A, B, lds, t + 2, m0, n0, tid, wid);
        asm volatile("s_waitcnt vmcnt(6)" ::: "memory");
        __builtin_amdgcn_s_barrier();
        mfma_quad(acc[3], avHi, bvLo);
        __builtin_amdgcn_s_barrier();
    }

    // Epilogue (C/D layout: col = lane&15, row = (lane>>4)*4 + reg).
    // Nontemporal: C written once, never re-read -> don't churn L3.
#pragma unroll
    for (int q = 0; q < 4; ++q) {
        const int mqe = q >> 1;
        const int nqe = (q == 1 || q == 2) ? 1 : 0;
#pragma unroll
        for (int n = 0; n < 2; ++n) {
            const int col = n0 + nqe * 128 + wc * 32 + n * 16 + l15;
            const float bval = bias[col];
#pragma unroll
            for (int m = 0; m < 4; ++m) {
                const int row = m0 + mqe * 128 + wr * 64 + m * 16 + kgrp * 4;
#pragma unroll
                for (int r = 0; r < 4; ++r)
                    __builtin_nontemporal_store(acc[q][m][n][r] + bval,
                        &C[(size_t)(row + r) * N_DIM + col]);
            }
        }
    }
}

// ---------------------------------------------------------------------------
extern "C" void kernel_launch(void* const* d_in, const int* in_sizes, int n_in,
                              void* d_out, int out_size, void* d_ws, size_t ws_size,
                              hipStream_t stream)
{
    const float* x      = (const float*)d_in[0];  // [4,2048,4096] f32
    const int*   codes  = (const int*)d_in[1];    // [704512,64] i32
    const float* absmax = (const float*)d_in[2];  // [704512] f32
    const float* bias   = (const float*)d_in[3];  // [11008] f32
    float* out = (float*)d_out;                   // [4,2048,11008] f32

    const size_t w_bytes = (size_t)N_DIM * K_DIM * sizeof(__hip_bfloat16);
    const size_t x_bytes = (size_t)M_DIM * K_DIM * sizeof(__hip_bfloat16);
    if (ws_size < w_bytes + x_bytes) {
        fprintf(stderr, "kernel_launch: ws_size=%zu < needed %zu\n",
                ws_size, w_bytes + x_bytes);
        return;
    }
    __hip_bfloat16* wbf = (__hip_bfloat16*)d_ws;
    __hip_bfloat16* xbf = (__hip_bfloat16*)((char*)d_ws + w_bytes);

    // Allow 128 KiB dynamic LDS (idempotent host-side call; capture-safe).
    hipFuncSetAttribute((const void*)gemm_bf16_8phase,
                        hipFuncAttributeMaxDynamicSharedMemorySize, 131072);

    fp4_dequant_kernel<<<dim3(22016), dim3(256), 0, stream>>>(codes, absmax, wbf);
    f32_to_bf16_kernel<<<dim3(16384), dim3(256), 0, stream>>>(x, xbf);
    gemm_bf16_8phase<<<dim3(NWG), dim3(512), 131072, stream>>>(xbf, wbf, bias, out);
}

// Round 6
// 833.449 us; speedup vs baseline: 1.6417x; 1.0008x over previous
//
#include <hip/hip_runtime.h>
#include <hip/hip_bf16.h>
#include <stdint.h>
#include <stdio.h>

// Problem geometry (fixed by the reference)
#define M_DIM 8192    // 4*2048
#define K_DIM 4096    // IN_FEATURES
#define N_DIM 11008   // OUT_FEATURES

// 256^2 8-phase template (m201 structure)
#define BM 256
#define BN 256
#define BK 64
#define NT (K_DIM / BK)           // 64 K-tiles (power of 2 -> & wrap ok)
#define TILES_M (M_DIM / BM)      // 32
#define TILES_N (N_DIM / BN)      // 43
#define NWG (TILES_M * TILES_N)   // 1376 (%8==0 -> simple XCD swizzle bijective)

typedef __bf16 bf16x8 __attribute__((ext_vector_type(8)));
typedef float f32x4 __attribute__((ext_vector_type(4)));

__device__ __constant__ float kFp4Code[16] = {
    0.0f,           0.0052083333f,  0.6666666666f, 1.0f,
    0.3333333333f,  0.5f,           0.1666666666f, 0.25f,
    -0.0f,          -0.0052083333f, -0.6666666666f, -1.0f,
    -0.3333333333f, -0.5f,          -0.1666666666f, -0.25f
};

// ---------------------------------------------------------------------------
// Kernel 1: FP4 dequant -> bf16 W [N_DIM][K_DIM]
// ---------------------------------------------------------------------------
__global__ __launch_bounds__(256) void fp4_dequant_kernel(
    const int* __restrict__ codes, const float* __restrict__ absmax,
    __hip_bfloat16* __restrict__ w)
{
    __shared__ float lut[16];
    if (threadIdx.x < 16) lut[threadIdx.x] = kFp4Code[threadIdx.x];
    __syncthreads();

    const int t = blockIdx.x * 256 + threadIdx.x;  // < 5,636,096
    const int4* cp = (const int4*)codes;
    const int4 c0 = cp[2 * t];
    const int4 c1 = cp[2 * t + 1];
    const float am = absmax[t >> 3];

    union { int4 v; __hip_bfloat16 h[8]; } u;
    u.h[0] = __float2bfloat16(lut[c0.x & 15] * am);
    u.h[1] = __float2bfloat16(lut[c0.y & 15] * am);
    u.h[2] = __float2bfloat16(lut[c0.z & 15] * am);
    u.h[3] = __float2bfloat16(lut[c0.w & 15] * am);
    u.h[4] = __float2bfloat16(lut[c1.x & 15] * am);
    u.h[5] = __float2bfloat16(lut[c1.y & 15] * am);
    u.h[6] = __float2bfloat16(lut[c1.z & 15] * am);
    u.h[7] = __float2bfloat16(lut[c1.w & 15] * am);
    ((int4*)w)[t] = u.v;
}

// ---------------------------------------------------------------------------
// Kernel 2: x fp32 -> bf16  [M_DIM][K_DIM]
// ---------------------------------------------------------------------------
__global__ __launch_bounds__(256) void f32_to_bf16_kernel(
    const float* __restrict__ x, __hip_bfloat16* __restrict__ y)
{
    const int t = blockIdx.x * 256 + threadIdx.x;  // < 4,194,304
    const float4* xp = (const float4*)x;
    const float4 a = xp[2 * t];
    const float4 b = xp[2 * t + 1];
    union { int4 v; __hip_bfloat16 h[8]; } u;
    u.h[0] = __float2bfloat16(a.x);
    u.h[1] = __float2bfloat16(a.y);
    u.h[2] = __float2bfloat16(a.z);
    u.h[3] = __float2bfloat16(a.w);
    u.h[4] = __float2bfloat16(b.x);
    u.h[5] = __float2bfloat16(b.y);
    u.h[6] = __float2bfloat16(b.z);
    u.h[7] = __float2bfloat16(b.w);
    ((int4*)y)[t] = u.v;
}

// ---------------------------------------------------------------------------
// Kernel 3: bf16 GEMM, C = A * B^T + bias   (256x256 tile, 8-phase schedule)
//
// Round-6 change vs round-5: ADDRESS PRECOMPUTATION ONLY. The barrier /
// vmcnt / issue-slot schedule is slot-for-slot identical to round 5 (verified
// incl. prologue order and tail wrap). Round-5 PMC: VALUBusy 18% ~= 230
// cyc/phase of address arithmetic sitting BEFORE ds_read/gload issue ->
// directly on the critical path.
//   - Fragment reads: r&7 == l15&7 (m*16, wr*64 don't touch low bits), so
//     the XOR column is m-independent -> ONE per-lane base pointer per
//     (operand, ks); m/n/hi variations are compile-time ds offsets
//     (+2048*m, +16384). Buffer toggle made compile-time by unrolling the
//     K-loop by 2 (template<BUF>).
//   - Stage sources: per-lane element offsets precomputed once; per-tile
//     K-advance is a wave-uniform koff (2 SALU per tile). 1 VALU add/use.
//
// LDS (128 KiB): 2 dbuf x { A-lo@0, A-hi@16384, B-lo@32768, B-hi@49152 },
// buffer b at b*65536. XOR involution swizzle (round-2-proven, 0 conflicts):
// LDS slot (row,c) holds global chunk (row, c^(row&7)); gload_lds dest LINEAR.
// Stage stream (per tile t, buf=t&1): P0: A-hi(t+1); P1: A-lo(t+2);
// P2: B-lo(t+2); P3: B-hi(t+2) + the ONE vmcnt(6) per tile.
// ---------------------------------------------------------------------------
#define STAGE(gbase, eoff, loff)                                              \
    __builtin_amdgcn_global_load_lds(                                         \
        (const __attribute__((address_space(1))) void*)((gbase) + (eoff)),    \
        (__attribute__((address_space(3))) void*)(lds + (loff)), 16, 0, 0)

__device__ __forceinline__ void mfma_quad(
    f32x4 (&accq)[4][2], bf16x8 (&av)[4][2], bf16x8 (&bv)[2][2])
{
    __builtin_amdgcn_s_setprio(1);
#pragma unroll
    for (int m = 0; m < 4; ++m)
#pragma unroll
        for (int n = 0; n < 2; ++n)
#pragma unroll
            for (int ks = 0; ks < 2; ++ks)
                accq[m][n] = __builtin_amdgcn_mfma_f32_16x16x32_bf16(
                    av[m][ks], bv[n][ks], accq[m][n], 0, 0, 0);
    __builtin_amdgcn_s_setprio(0);
}

template<int BUF>
__device__ __forceinline__ void tile_body(
    int t, f32x4 (&acc)[4][4][2],
    const __hip_bfloat16* __restrict__ A, const __hip_bfloat16* __restrict__ B,
    char* lds,
    const int (&sA_lo)[2], const int (&sA_hi)[2],
    const int (&sB_lo)[2], const int (&sB_hi)[2],
    int dst0, int dst1,
    const char* pA0, const char* pA1, const char* pB0, const char* pB1)
{
    constexpr int LB  = BUF * 65536;         // this tile's buffer
    constexpr int LB1 = (BUF ^ 1) * 65536;   // (t+1)'s buffer
    const int koff1 = ((t + 1) & (NT - 1)) * 64;   // wave-uniform (SALU)
    const int koff2 = ((t + 2) & (NT - 1)) * 64;

    bf16x8 avLo[4][2], avHi[4][2], bvLo[2][2], bvHi[2][2];

    // ---- P0: Q(0,0): read A-lo + B-lo (12 b128); stage A-hi(t+1) ----
#pragma unroll
    for (int m = 0; m < 4; ++m) {
        avLo[m][0] = *(const bf16x8*)(pA0 + LB + m * 2048);
        avLo[m][1] = *(const bf16x8*)(pA1 + LB + m * 2048);
    }
#pragma unroll
    for (int n = 0; n < 2; ++n) {
        bvLo[n][0] = *(const bf16x8*)(pB0 + LB + n * 2048);
        bvLo[n][1] = *(const bf16x8*)(pB1 + LB + n * 2048);
    }
    STAGE(A, sA_hi[0] + koff1, LB1 + 16384 + dst0);
    STAGE(A, sA_hi[1] + koff1, LB1 + 16384 + dst1);
    __builtin_amdgcn_s_barrier();
    asm volatile("s_waitcnt lgkmcnt(0)" ::: "memory");
    mfma_quad(acc[0], avLo, bvLo);
    __builtin_amdgcn_s_barrier();

    // ---- P1: Q(0,1): read B-hi (4); stage A-lo(t+2); A-lo held ----
#pragma unroll
    for (int n = 0; n < 2; ++n) {
        bvHi[n][0] = *(const bf16x8*)(pB0 + LB + 16384 + n * 2048);
        bvHi[n][1] = *(const bf16x8*)(pB1 + LB + 16384 + n * 2048);
    }
    STAGE(A, sA_lo[0] + koff2, LB + dst0);
    STAGE(A, sA_lo[1] + koff2, LB + dst1);
    __builtin_amdgcn_s_barrier();
    asm volatile("s_waitcnt lgkmcnt(0)" ::: "memory");
    mfma_quad(acc[1], avLo, bvHi);
    __builtin_amdgcn_s_barrier();

    // ---- P2: Q(1,1): read A-hi (8); stage B-lo(t+2); B-hi held ----
#pragma unroll
    for (int m = 0; m < 4; ++m) {
        avHi[m][0] = *(const bf16x8*)(pA0 + LB + 16384 + m * 2048);
        avHi[m][1] = *(const bf16x8*)(pA1 + LB + 16384 + m * 2048);
    }
    STAGE(B, sB_lo[0] + koff2, LB + 32768 + dst0);
    STAGE(B, sB_lo[1] + koff2, LB + 32768 + dst1);
    __builtin_amdgcn_s_barrier();
    asm volatile("s_waitcnt lgkmcnt(0)" ::: "memory");
    mfma_quad(acc[2], avHi, bvHi);
    __builtin_amdgcn_s_barrier();

    // ---- P3: Q(1,0): no ds_read (A-hi, B-lo held); stage B-hi(t+2);
    //      the ONE vmcnt per tile: 3 newest halves stay in flight ----
    STAGE(B, sB_hi[0] + koff2, LB + 49152 + dst0);
    STAGE(B, sB_hi[1] + koff2, LB + 49152 + dst1);
    asm volatile("s_waitcnt vmcnt(6)" ::: "memory");
    __builtin_amdgcn_s_barrier();
    mfma_quad(acc[3], avHi, bvLo);
    __builtin_amdgcn_s_barrier();
}

__global__ __launch_bounds__(512, 2) void gemm_bf16_8phase(
    const __hip_bfloat16* __restrict__ A, const __hip_bfloat16* __restrict__ B,
    const float* __restrict__ bias, float* __restrict__ C)
{
    extern __shared__ char lds[];  // 131072 B

    const int tid = threadIdx.x;
    const int lane = tid & 63;
    const int wid = tid >> 6;       // 0..7
    const int wr = wid >> 2;        // 0..1 (M split)
    const int wc = wid & 3;         // 0..3 (N split)
    const int l15 = lane & 15;
    const int kgrp = lane >> 4;

    // XCD-aware bijective swizzle; consecutive same-XCD blocks share tile_n
    // -> 2 MB B panel stays L2-resident.
    const int wg = blockIdx.x;
    const int swz = (wg & 7) * (NWG / 8) + (wg >> 3);
    const int tile_m = swz % TILES_M;
    const int tile_n = swz / TILES_M;
    const int m0 = tile_m * BM;
    const int n0 = tile_n * BN;

    // ---- Precomputed stage-source element offsets (per lane, once) ----
    int sA_lo[2], sA_hi[2], sB_lo[2], sB_hi[2];
#pragma unroll
    for (int c = 0; c < 2; ++c) {
        const int idx = c * 512 + tid;          // 0..1023 chunk id (linear LDS)
        const int row = idx >> 3;               // 0..127
        const int scol = (idx & 7) ^ (row & 7); // pre-swizzled source chunk
        sA_lo[c] = (m0 + row) * K_DIM + scol * 8;
        sA_hi[c] = sA_lo[c] + 128 * K_DIM;
        sB_lo[c] = (n0 + row) * K_DIM + scol * 8;
        sB_hi[c] = sB_lo[c] + 128 * K_DIM;
    }
    const int dst0 = wid * 1024;          // (c*512 + wid*64)*16, c=0
    const int dst1 = 8192 + wid * 1024;   // c=1

    // ---- Precomputed fragment-read base pointers (buf0; buf1 = +65536) ----
    // Full addr = base + {A-hi/B-hi: +16384} + m|n * 2048  (compile-time imms)
    const int xlo = l15 & 7;
    const char* pA0 = lds + (wr * 64 + l15) * 128 + ((kgrp) ^ xlo) * 16;
    const char* pA1 = lds + (wr * 64 + l15) * 128 + ((4 + kgrp) ^ xlo) * 16;
    const char* pB0 = lds + 32768 + (wc * 32 + l15) * 128 + ((kgrp) ^ xlo) * 16;
    const char* pB1 = lds + 32768 + (wc * 32 + l15) * 128 + ((4 + kgrp) ^ xlo) * 16;

    // acc quadrants: 0=(0,0) 1=(0,1) 2=(1,1) 3=(1,0)  (mq,nq)
    f32x4 acc[4][4][2];
#pragma unroll
    for (int q = 0; q < 4; ++q)
#pragma unroll
        for (int m = 0; m < 4; ++m)
#pragma unroll
            for (int n = 0; n < 2; ++n)
                acc[q][m][n] = (f32x4){0.f, 0.f, 0.f, 0.f};

    // Prologue: 7 halves, same issue order as round 5:
    // A-lo(0), B-lo(0), B-hi(0), A-hi(0), A-lo(1), B-lo(1), B-hi(1)
    STAGE(A, sA_lo[0], dst0);                 STAGE(A, sA_lo[1], dst1);
    STAGE(B, sB_lo[0], 32768 + dst0);         STAGE(B, sB_lo[1], 32768 + dst1);
    STAGE(B, sB_hi[0], 49152 + dst0);         STAGE(B, sB_hi[1], 49152 + dst1);
    STAGE(A, sA_hi[0], 16384 + dst0);         STAGE(A, sA_hi[1], 16384 + dst1);
    STAGE(A, sA_lo[0] + 64, 65536 + dst0);    STAGE(A, sA_lo[1] + 64, 65536 + dst1);
    STAGE(B, sB_lo[0] + 64, 98304 + dst0);    STAGE(B, sB_lo[1] + 64, 98304 + dst1);
    STAGE(B, sB_hi[0] + 64, 114688 + dst0);   STAGE(B, sB_hi[1] + 64, 114688 + dst1);
    asm volatile("s_waitcnt vmcnt(6)" ::: "memory"); // tile-0's 4 halves landed
    __builtin_amdgcn_s_barrier();

    for (int t = 0; t < NT; t += 2) {
        tile_body<0>(t,     acc, A, B, lds, sA_lo, sA_hi, sB_lo, sB_hi,
                     dst0, dst1, pA0, pA1, pB0, pB1);
        tile_body<1>(t + 1, acc, A, B, lds, sA_lo, sA_hi, sB_lo, sB_hi,
                     dst0, dst1, pA0, pA1, pB0, pB1);
    }

    // Epilogue (C/D layout: col = lane&15, row = (lane>>4)*4 + reg).
    // Nontemporal: C written once, never re-read -> don't churn L3.
#pragma unroll
    for (int q = 0; q < 4; ++q) {
        const int mqe = q >> 1;
        const int nqe = (q == 1 || q == 2) ? 1 : 0;
#pragma unroll
        for (int n = 0; n < 2; ++n) {
            const int col = n0 + nqe * 128 + wc * 32 + n * 16 + l15;
            const float bval = bias[col];
#pragma unroll
            for (int m = 0; m < 4; ++m) {
                const int row = m0 + mqe * 128 + wr * 64 + m * 16 + kgrp * 4;
#pragma unroll
                for (int r = 0; r < 4; ++r)
                    __builtin_nontemporal_store(acc[q][m][n][r] + bval,
                        &C[(size_t)(row + r) * N_DIM + col]);
            }
        }
    }
}

// ---------------------------------------------------------------------------
extern "C" void kernel_launch(void* const* d_in, const int* in_sizes, int n_in,
                              void* d_out, int out_size, void* d_ws, size_t ws_size,
                              hipStream_t stream)
{
    const float* x      = (const float*)d_in[0];  // [4,2048,4096] f32
    const int*   codes  = (const int*)d_in[1];    // [704512,64] i32
    const float* absmax = (const float*)d_in[2];  // [704512] f32
    const float* bias   = (const float*)d_in[3];  // [11008] f32
    float* out = (float*)d_out;                   // [4,2048,11008] f32

    const size_t w_bytes = (size_t)N_DIM * K_DIM * sizeof(__hip_bfloat16);
    const size_t x_bytes = (size_t)M_DIM * K_DIM * sizeof(__hip_bfloat16);
    if (ws_size < w_bytes + x_bytes) {
        fprintf(stderr, "kernel_launch: ws_size=%zu < needed %zu\n",
                ws_size, w_bytes + x_bytes);
        return;
    }
    __hip_bfloat16* wbf = (__hip_bfloat16*)d_ws;
    __hip_bfloat16* xbf = (__hip_bfloat16*)((char*)d_ws + w_bytes);

    // Allow 128 KiB dynamic LDS (idempotent host-side call; capture-safe).
    hipFuncSetAttribute((const void*)gemm_bf16_8phase,
                        hipFuncAttributeMaxDynamicSharedMemorySize, 131072);

    fp4_dequant_kernel<<<dim3(22016), dim3(256), 0, stream>>>(codes, absmax, wbf);
    f32_to_bf16_kernel<<<dim3(16384), dim3(256), 0, stream>>>(x, xbf);
    gemm_bf16_8phase<<<dim3(NWG), dim3(512), 131072, stream>>>(xbf, wbf, bias, out);
}